// Round 1
// baseline (184.307 us; speedup 1.0000x reference)
//
#include <hip/hip_runtime.h>

#define EPS 1e-20f

// ws layout (floats): [0,288) sw = softplus(spatial_weight) [c*9+k]
//                     [288,1312) cwT = softplus(channel_weight) transposed [c*32+o]
//                     [1312] 1/sum(sw), [1313] 1/sum(cw)
__global__ void prep_weights(const float* __restrict__ channel_weight, // [32*32] = [o][c]
                             const float* __restrict__ spatial_weight, // [32*9]
                             float* __restrict__ ws) {
    __shared__ float red[256];
    int tid = threadIdx.x;
    float local_sw = 0.f, local_cw = 0.f;
    for (int i = tid; i < 288; i += 256) {
        float x = spatial_weight[i];
        float v = fmaxf(x, 0.f) + log1pf(expf(-fabsf(x)));
        ws[i] = v;
        local_sw += v;
    }
    for (int i = tid; i < 1024; i += 256) {
        float x = channel_weight[i];   // i = o*32 + c
        float v = fmaxf(x, 0.f) + log1pf(expf(-fabsf(x)));
        int o = i >> 5, c = i & 31;
        ws[288 + c * 32 + o] = v;      // transposed store
        local_cw += v;
    }
    red[tid] = local_sw;
    __syncthreads();
    for (int s = 128; s > 0; s >>= 1) {
        if (tid < s) red[tid] += red[tid + s];
        __syncthreads();
    }
    if (tid == 0) ws[1312] = 1.0f / red[0];
    __syncthreads();
    red[tid] = local_cw;
    __syncthreads();
    for (int s = 128; s > 0; s >>= 1) {
        if (tid < s) red[tid] += red[tid + s];
        __syncthreads();
    }
    if (tid == 0) ws[1313] = 1.0f / red[0];
}

// B=4, Cin=Cout=32, H=W=256, K=3, pad=1, stride=1, dil=1
__global__ __launch_bounds__(256) void fused_structnconv(
    const float* __restrict__ d,
    const float* __restrict__ cd,
    const float* __restrict__ sp,     // s_prod_roll [B,Cin,9,H,W]
    const float* __restrict__ wsbuf,
    const float* __restrict__ bias,   // [32]
    float* __restrict__ out)          // d_out [4,32,256,256] then cd_out
{
    const int W = 256, Cin = 32;
    const int w = threadIdx.x;
    const int h = blockIdx.x & 255;
    const int b = blockIdx.x >> 8;

    const float* __restrict__ sw  = wsbuf;         // [32*9]
    const float* __restrict__ cwT = wsbuf + 288;   // [c*32+o]
    const float inv_sum_sw = wsbuf[1312];
    const float inv_sum_cw = wsbuf[1313];

    float nom2[32], den2[32];
    #pragma unroll
    for (int o = 0; o < 32; ++o) { nom2[o] = 0.f; den2[o] = 0.f; }

    const size_t plane = 65536;                       // H*W
    const size_t img_base = (size_t)b * Cin * plane;  // channel-0 offset of this image
    const int pix = h * W + w;

    for (int c = 0; c < Cin; ++c) {
        const float* __restrict__ dC  = d  + img_base + (size_t)c * plane;
        const float* __restrict__ cdC = cd + img_base + (size_t)c * plane;
        const float* __restrict__ spC = sp + ((size_t)b * Cin + c) * 9 * plane + pix;

        float nom = 0.f, den = 0.f;
        #pragma unroll
        for (int k = 0; k < 9; ++k) {
            const int di = k / 3 - 1, dj = k % 3 - 1;
            const int hh = h + di, ww = w + dj;
            const bool valid = ((unsigned)hh < 256u) && ((unsigned)ww < 256u);
            const int hc = min(max(hh, 0), 255);
            const int wc = min(max(ww, 0), 255);
            const float dv  = dC[hc * W + wc];
            const float cdv = cdC[hc * W + wc];
            const float spv = spC[(size_t)k * plane];
            const float cdp = valid ? cdv * spv : 0.f;
            const float swk = sw[c * 9 + k];          // uniform -> scalar load
            nom = fmaf(cdp * dv, swk, nom);
            den = fmaf(cdp, swk, den);
        }
        const float dsp  = nom / (den + EPS);
        const float cdsp = den * inv_sum_sw;
        const float t    = cdsp * dsp;

        #pragma unroll
        for (int o = 0; o < 32; ++o) {
            const float cwv = cwT[c * 32 + o];        // uniform, contiguous per c
            nom2[o] = fmaf(t,    cwv, nom2[o]);
            den2[o] = fmaf(cdsp, cwv, den2[o]);
        }
    }

    const size_t out_base = (size_t)b * 32 * plane + pix;
    #pragma unroll
    for (int o = 0; o < 32; ++o) {
        const float dout  = nom2[o] / (den2[o] + EPS) + bias[o];
        const float cdout = den2[o] * inv_sum_cw;     // STRIDE=1
        out[out_base + (size_t)o * plane] = dout;
        out[8388608 + out_base + (size_t)o * plane] = cdout;
    }
}

extern "C" void kernel_launch(void* const* d_in, const int* in_sizes, int n_in,
                              void* d_out, int out_size, void* d_ws, size_t ws_size,
                              hipStream_t stream) {
    const float* d    = (const float*)d_in[0];
    const float* cd   = (const float*)d_in[1];
    // d_in[2] = s, d_in[3] = cs : unused in forward
    const float* sp   = (const float*)d_in[4];
    const float* cwt  = (const float*)d_in[5];
    const float* swt  = (const float*)d_in[6];
    const float* bias = (const float*)d_in[7];
    float* out = (float*)d_out;
    float* ws  = (float*)d_ws;

    prep_weights<<<1, 256, 0, stream>>>(cwt, swt, ws);
    fused_structnconv<<<1024, 256, 0, stream>>>(d, cd, sp, ws, bias, out);
}

// Round 2
// 122.311 us; speedup vs baseline: 1.5069x; 1.5069x over previous
//
#include <hip/hip_runtime.h>

#define EPS 1e-20f

// ws layout (floats): [0,288)   sw  = softplus(spatial_weight) [c*9+k]
//                     [288,1312) cwT = softplus(channel_weight) transposed [c*32+o]
//                     [1312] 1/sum(sw), [1313] 1/sum(cw)
//                     [4096, 4096+8388608)            t    = cd_spatial*d_spatial  [b][c][pix]
//                     [4096+8388608, 4096+16777216)   cdsp = cd_spatial            [b][c][pix]
__global__ void prep_weights(const float* __restrict__ channel_weight, // [32*32] = [o][c]
                             const float* __restrict__ spatial_weight, // [32*9]
                             float* __restrict__ ws) {
    __shared__ float red[256];
    int tid = threadIdx.x;
    float local_sw = 0.f, local_cw = 0.f;
    for (int i = tid; i < 288; i += 256) {
        float x = spatial_weight[i];
        float v = fmaxf(x, 0.f) + log1pf(expf(-fabsf(x)));
        ws[i] = v;
        local_sw += v;
    }
    for (int i = tid; i < 1024; i += 256) {
        float x = channel_weight[i];   // i = o*32 + c
        float v = fmaxf(x, 0.f) + log1pf(expf(-fabsf(x)));
        int o = i >> 5, c = i & 31;
        ws[288 + c * 32 + o] = v;      // transposed store
        local_cw += v;
    }
    red[tid] = local_sw;
    __syncthreads();
    for (int s = 128; s > 0; s >>= 1) {
        if (tid < s) red[tid] += red[tid + s];
        __syncthreads();
    }
    if (tid == 0) ws[1312] = 1.0f / red[0];
    __syncthreads();
    red[tid] = local_cw;
    __syncthreads();
    for (int s = 128; s > 0; s >>= 1) {
        if (tid < s) red[tid] += red[tid + s];
        __syncthreads();
    }
    if (tid == 0) ws[1313] = 1.0f / red[0];
}

// ---------------- Stage 1: per-channel 3x3 normalized conv -> t, cdsp ----------------
// grid: 8192 blocks = (b*32+c)*64 + rowgroup ; block: 256 threads = 4 rows x 64 quads
__global__ __launch_bounds__(256) void stage1(
    const float* __restrict__ d,
    const float* __restrict__ cd,
    const float* __restrict__ sp,     // [B,Cin,9,H,W]
    const float* __restrict__ wsbuf,
    float* __restrict__ tbuf,
    float* __restrict__ cdspbuf)
{
    const int plane = 65536;
    const int rg = blockIdx.x & 63;
    const int bc = blockIdx.x >> 6;       // b*32+c
    const int c  = bc & 31;
    const int r  = threadIdx.x >> 6;      // 0..3
    const int qw = threadIdx.x & 63;      // quad index in row
    const int h  = rg * 4 + r;
    const int cb = qw * 4;                // first column of this quad

    const float* __restrict__ sw = wsbuf + c * 9;     // uniform per block
    const float inv_sum_sw = wsbuf[1312];

    const float* __restrict__ dC  = d  + (size_t)bc * plane;
    const float* __restrict__ cdC = cd + (size_t)bc * plane;
    const float* __restrict__ spC = sp + (size_t)bc * 9 * plane + h * 256 + cb;

    float4 spv[9];
    #pragma unroll
    for (int k = 0; k < 9; ++k) spv[k] = *(const float4*)(spC + (size_t)k * plane);

    float dr[3][6], cr[3][6];             // cols cb-1 .. cb+4
    #pragma unroll
    for (int i = 0; i < 3; ++i) {
        const int hh = h + i - 1;
        const int hc = min(max(hh, 0), 255);
        const float* __restrict__ drow = dC  + hc * 256;
        const float* __restrict__ crow = cdC + hc * 256;
        float4 dv = *(const float4*)(drow + cb);
        float4 cv = *(const float4*)(crow + cb);
        dr[i][1] = dv.x; dr[i][2] = dv.y; dr[i][3] = dv.z; dr[i][4] = dv.w;
        cr[i][1] = cv.x; cr[i][2] = cv.y; cr[i][3] = cv.z; cr[i][4] = cv.w;
        dr[i][0] = drow[max(cb - 1, 0)];
        cr[i][0] = crow[max(cb - 1, 0)];
        dr[i][5] = drow[min(cb + 4, 255)];
        cr[i][5] = crow[min(cb + 4, 255)];
    }

    const bool rowv0 = (h >= 1), rowv2 = (h <= 254);
    float nom[4] = {0.f, 0.f, 0.f, 0.f}, den[4] = {0.f, 0.f, 0.f, 0.f};
    #pragma unroll
    for (int i = 0; i < 3; ++i) {
        const bool rv = (i == 0) ? rowv0 : ((i == 2) ? rowv2 : true);
        #pragma unroll
        for (int j = 0; j < 3; ++j) {
            const int k = i * 3 + j;
            const float swk = sw[k];
            const float spk[4] = {spv[k].x, spv[k].y, spv[k].z, spv[k].w};
            #pragma unroll
            for (int p = 0; p < 4; ++p) {
                const int ww = cb + p + j - 1;
                const bool valid = rv && ((unsigned)ww < 256u);
                const float cdp = valid ? cr[i][p + j] * spk[p] : 0.f;
                nom[p] = fmaf(cdp * dr[i][p + j], swk, nom[p]);
                den[p] = fmaf(cdp, swk, den[p]);
            }
        }
    }

    float4 t4, c4;
    float tp[4], cp[4];
    #pragma unroll
    for (int p = 0; p < 4; ++p) {
        const float dsp  = nom[p] / (den[p] + EPS);
        const float cdsp = den[p] * inv_sum_sw;
        tp[p] = cdsp * dsp; cp[p] = cdsp;
    }
    t4.x = tp[0]; t4.y = tp[1]; t4.z = tp[2]; t4.w = tp[3];
    c4.x = cp[0]; c4.y = cp[1]; c4.z = cp[2]; c4.w = cp[3];
    const size_t off = (size_t)bc * plane + h * 256 + cb;
    *(float4*)(tbuf + off)    = t4;
    *(float4*)(cdspbuf + off) = c4;
}

// ---------------- Stage 2: 1x1 channel mixing via LDS tile ----------------
// grid: 2048 blocks, each covers 128 pixels of one image.
// block: 256 threads = 8 o-groups (4 o each) x 32 pixel-quads (4 px each)
__global__ __launch_bounds__(256) void stage2(
    const float* __restrict__ tbuf,
    const float* __restrict__ cdspbuf,
    const float* __restrict__ wsbuf,
    const float* __restrict__ bias,   // [32]
    float* __restrict__ out)
{
    __shared__ float lt[32 * 128];    // [c][j][quad] = c*128 + j*32 + q
    __shared__ float lc[32 * 128];
    __shared__ float lcw[1024];       // [c][o]

    const int plane = 65536;
    const int tid = threadIdx.x;
    const int b = blockIdx.x >> 9;                 // 512 blocks per image
    const int pixbase = (blockIdx.x & 511) * 128;

    // phase 1: cooperative load of t/cdsp tile + weights
    {
        const int q = tid & 31;
        const int csub = tid >> 5;                 // 0..7
        #pragma unroll
        for (int i = 0; i < 4; ++i) {
            const int c = i * 8 + csub;
            const size_t g = (size_t)(b * 32 + c) * plane + pixbase + q * 4;
            float4 tv = *(const float4*)(tbuf + g);
            float4 cv = *(const float4*)(cdspbuf + g);
            lt[c * 128 + 0 * 32 + q] = tv.x;
            lt[c * 128 + 1 * 32 + q] = tv.y;
            lt[c * 128 + 2 * 32 + q] = tv.z;
            lt[c * 128 + 3 * 32 + q] = tv.w;
            lc[c * 128 + 0 * 32 + q] = cv.x;
            lc[c * 128 + 1 * 32 + q] = cv.y;
            lc[c * 128 + 2 * 32 + q] = cv.z;
            lc[c * 128 + 3 * 32 + q] = cv.w;
        }
        #pragma unroll
        for (int i = 0; i < 4; ++i) lcw[i * 256 + tid] = wsbuf[288 + i * 256 + tid];
    }
    __syncthreads();

    const int og = tid >> 5;       // 0..7 -> o = og*4 .. og*4+3
    const int q  = tid & 31;       // pixel quad
    const int o0 = og * 4;

    float n2[4][4], d2[4][4];
    #pragma unroll
    for (int oi = 0; oi < 4; ++oi)
        #pragma unroll
        for (int j = 0; j < 4; ++j) { n2[oi][j] = 0.f; d2[oi][j] = 0.f; }

    for (int c = 0; c < 32; ++c) {
        float tq[4], cq[4];
        #pragma unroll
        for (int j = 0; j < 4; ++j) {
            tq[j] = lt[c * 128 + j * 32 + q];
            cq[j] = lc[c * 128 + j * 32 + q];
        }
        const float4 cw4 = *(const float4*)&lcw[c * 32 + o0];
        const float cwv[4] = {cw4.x, cw4.y, cw4.z, cw4.w};
        #pragma unroll
        for (int oi = 0; oi < 4; ++oi)
            #pragma unroll
            for (int j = 0; j < 4; ++j) {
                n2[oi][j] = fmaf(tq[j], cwv[oi], n2[oi][j]);
                d2[oi][j] = fmaf(cq[j], cwv[oi], d2[oi][j]);
            }
    }

    const float inv_sum_cw = wsbuf[1313];
    #pragma unroll
    for (int oi = 0; oi < 4; ++oi) {
        const int o = o0 + oi;
        const float bo = bias[o];
        float4 dv, cv;
        float dvv[4], cvv[4];
        #pragma unroll
        for (int j = 0; j < 4; ++j) {
            dvv[j] = n2[oi][j] / (d2[oi][j] + EPS) + bo;
            cvv[j] = d2[oi][j] * inv_sum_cw;   // STRIDE=1
        }
        dv.x = dvv[0]; dv.y = dvv[1]; dv.z = dvv[2]; dv.w = dvv[3];
        cv.x = cvv[0]; cv.y = cvv[1]; cv.z = cvv[2]; cv.w = cvv[3];
        const size_t po = (size_t)(b * 32 + o) * plane + pixbase + q * 4;
        *(float4*)(out + po)           = dv;
        *(float4*)(out + 8388608 + po) = cv;
    }
}

// ---------------- Fallback (R0 fused kernel) if ws too small ----------------
__global__ __launch_bounds__(256) void fused_structnconv(
    const float* __restrict__ d,
    const float* __restrict__ cd,
    const float* __restrict__ sp,
    const float* __restrict__ wsbuf,
    const float* __restrict__ bias,
    float* __restrict__ out)
{
    const int W = 256, Cin = 32;
    const int w = threadIdx.x;
    const int h = blockIdx.x & 255;
    const int b = blockIdx.x >> 8;

    const float* __restrict__ sw  = wsbuf;
    const float* __restrict__ cwT = wsbuf + 288;
    const float inv_sum_sw = wsbuf[1312];
    const float inv_sum_cw = wsbuf[1313];

    float nom2[32], den2[32];
    #pragma unroll
    for (int o = 0; o < 32; ++o) { nom2[o] = 0.f; den2[o] = 0.f; }

    const size_t plane = 65536;
    const size_t img_base = (size_t)b * Cin * plane;
    const int pix = h * W + w;

    for (int c = 0; c < Cin; ++c) {
        const float* __restrict__ dC  = d  + img_base + (size_t)c * plane;
        const float* __restrict__ cdC = cd + img_base + (size_t)c * plane;
        const float* __restrict__ spC = sp + ((size_t)b * Cin + c) * 9 * plane + pix;

        float nom = 0.f, den = 0.f;
        #pragma unroll
        for (int k = 0; k < 9; ++k) {
            const int di = k / 3 - 1, dj = k % 3 - 1;
            const int hh = h + di, ww = w + dj;
            const bool valid = ((unsigned)hh < 256u) && ((unsigned)ww < 256u);
            const int hc = min(max(hh, 0), 255);
            const int wc = min(max(ww, 0), 255);
            const float dv  = dC[hc * W + wc];
            const float cdv = cdC[hc * W + wc];
            const float spv = spC[(size_t)k * plane];
            const float cdp = valid ? cdv * spv : 0.f;
            const float swk = sw[c * 9 + k];
            nom = fmaf(cdp * dv, swk, nom);
            den = fmaf(cdp, swk, den);
        }
        const float dsp  = nom / (den + EPS);
        const float cdsp = den * inv_sum_sw;
        const float t    = cdsp * dsp;

        #pragma unroll
        for (int o = 0; o < 32; ++o) {
            const float cwv = cwT[c * 32 + o];
            nom2[o] = fmaf(t,    cwv, nom2[o]);
            den2[o] = fmaf(cdsp, cwv, den2[o]);
        }
    }

    const size_t out_base = (size_t)b * 32 * plane + pix;
    #pragma unroll
    for (int o = 0; o < 32; ++o) {
        const float dout  = nom2[o] / (den2[o] + EPS) + bias[o];
        const float cdout = den2[o] * inv_sum_cw;
        out[out_base + (size_t)o * plane] = dout;
        out[8388608 + out_base + (size_t)o * plane] = cdout;
    }
}

extern "C" void kernel_launch(void* const* d_in, const int* in_sizes, int n_in,
                              void* d_out, int out_size, void* d_ws, size_t ws_size,
                              hipStream_t stream) {
    const float* d    = (const float*)d_in[0];
    const float* cd   = (const float*)d_in[1];
    // d_in[2] = s, d_in[3] = cs : unused in forward
    const float* sp   = (const float*)d_in[4];
    const float* cwt  = (const float*)d_in[5];
    const float* swt  = (const float*)d_in[6];
    const float* bias = (const float*)d_in[7];
    float* out = (float*)d_out;
    float* ws  = (float*)d_ws;

    prep_weights<<<1, 256, 0, stream>>>(cwt, swt, ws);

    const size_t need = (size_t)(4096 + 2 * 8388608) * sizeof(float);
    if (ws_size >= need) {
        float* tbuf    = ws + 4096;
        float* cdspbuf = ws + 4096 + 8388608;
        stage1<<<8192, 256, 0, stream>>>(d, cd, sp, ws, tbuf, cdspbuf);
        stage2<<<2048, 256, 0, stream>>>(tbuf, cdspbuf, ws, bias, out);
    } else {
        fused_structnconv<<<1024, 256, 0, stream>>>(d, cd, sp, ws, bias, out);
    }
}